// Round 1
// baseline (418.391 us; speedup 1.0000x reference)
//
#include <hip/hip_runtime.h>
#include <hip/hip_bf16.h>
#include <stdint.h>

// ---------- types / helpers ----------
typedef float  f32x4  __attribute__((ext_vector_type(4)));
typedef short  bf16x8 __attribute__((ext_vector_type(8)));
typedef short  bf16x4 __attribute__((ext_vector_type(4)));

#define MFMA16(A,B,C) __builtin_amdgcn_mfma_f32_16x16x32_bf16(A,B,C,0,0,0)

__device__ __forceinline__ short f2bf(float x){
    union { float f; uint32_t u; } v; v.f = x;
    uint32_t r = v.u + 0x7fffu + ((v.u >> 16) & 1u);   // RNE
    return (short)(r >> 16);
}
__device__ __forceinline__ float bf2f(short x){
    union { uint32_t u; float f; } v; v.u = ((uint32_t)(uint16_t)x) << 16;
    return v.f;
}
__device__ __forceinline__ bf16x8 pack8(f32x4 a, f32x4 b){
    bf16x8 r;
    r[0]=f2bf(a[0]); r[1]=f2bf(a[1]); r[2]=f2bf(a[2]); r[3]=f2bf(a[3]);
    r[4]=f2bf(b[0]); r[5]=f2bf(b[1]); r[6]=f2bf(b[2]); r[7]=f2bf(b[3]);
    return r;
}

// ---------- K0a: transpose Wq/Wk/Wv (fp32 [k][o]) -> WT bf16 [w][o][k] ----------
__global__ void k_prep_wt(const float* __restrict__ Wq, const float* __restrict__ Wk,
                          const float* __restrict__ Wv, short* __restrict__ WT){
    int blk = blockIdx.x;            // 192 = 3 * 64 tiles
    int w  = blk >> 6;
    int t  = blk & 63;
    int k0 = (t >> 3) << 6;
    int o0 = (t & 7) << 6;
    const float* W = (w == 0) ? Wq : ((w == 1) ? Wk : Wv);
    __shared__ float tile[64][65];
    int tx = threadIdx.x & 63, ty = threadIdx.x >> 6;    // ty 0..3
    #pragma unroll
    for (int i = 0; i < 64; i += 4)
        tile[ty + i][tx] = W[(size_t)(k0 + ty + i) * 512 + o0 + tx];
    __syncthreads();
    short* out = WT + (size_t)w * 512 * 512;
    #pragma unroll
    for (int i = 0; i < 64; i += 4)
        out[(size_t)(o0 + ty + i) * 512 + k0 + tx] = f2bf(tile[tx][ty + i]);
}

// ---------- K0b: WcatT bf16 [16ch][32c] (ch<8: We, ch>=8: Wg), bcat f32[16] ----------
__global__ void k_prep_wcat(const float* __restrict__ We, const float* __restrict__ Wg,
                            const float* __restrict__ be, const float* __restrict__ bg,
                            short* __restrict__ WcatT, float* __restrict__ bcat){
    int t = threadIdx.x;             // 512 threads
    int ch = t >> 5, c = t & 31;
    float v = (ch < 8) ? We[c * 8 + ch] : Wg[c * 8 + (ch - 8)];
    WcatT[ch * 32 + c] = f2bf(v);
    if (t < 16) bcat[t] = (t < 8) ? be[t] : bg[t - 8];
}

// ---------- K1: QKV projections ----------
// out = nodes @ W + b; q,k -> [b][h][l][64] bf16 ; v -> [b][h][64][l] bf16 (transposed)
__global__ void k_qkv(const float* __restrict__ nodes, const short* __restrict__ WT,
                      const float* __restrict__ bq, const float* __restrict__ bk,
                      const float* __restrict__ bv,
                      short* __restrict__ qb, short* __restrict__ kb, short* __restrict__ vTb){
    int bx = blockIdx.x;             // 1536
    int lt = bx & 255;
    int ob = bx >> 8;                // 0..5
    int wave = threadIdx.x >> 6, lane = threadIdx.x & 63;
    int lr = lane & 15, lg = lane >> 4;
    int row0 = lt << 4;              // global row (b*1024+l), tile of 16
    int og = ob * 256 + wave * 64;   // global col 0..1535
    int w  = og >> 9;                // 0=q,1=k,2=v
    int oo = og & 511;

    const short* Wp = WT + (size_t)w * 512 * 512;
    f32x4 acc[4] = {};
    const float* arow = nodes + (size_t)(row0 + lr) * 512 + lg * 8;
    #pragma unroll
    for (int kk = 0; kk < 16; ++kk){
        f32x4 a0 = *(const f32x4*)(arow + kk * 32);
        f32x4 a1 = *(const f32x4*)(arow + kk * 32 + 4);
        bf16x8 af = pack8(a0, a1);
        #pragma unroll
        for (int s = 0; s < 4; ++s){
            const short* bp = Wp + (size_t)(oo + s * 16 + lr) * 512 + kk * 32 + lg * 8;
            bf16x8 bfv = *(const bf16x8*)bp;
            acc[s] = MFMA16(af, bfv, acc[s]);
        }
    }
    const float* bias = (w == 0) ? bq : ((w == 1) ? bk : bv);
    int b  = row0 >> 10;
    int lb = (row0 & 1023) + lg * 4;
    #pragma unroll
    for (int s = 0; s < 4; ++s){
        int o = oo + s * 16 + lr;
        float bsv = bias[o];
        int h = o & 7, d = o >> 3;
        #pragma unroll
        for (int r = 0; r < 4; ++r){
            float v = acc[s][r] + bsv;
            short sv = f2bf(v);
            int l = lb + r;
            if (w == 0)       qb [((size_t)(b * 8 + h) * 1024 + l) * 64 + d] = sv;
            else if (w == 1)  kb [((size_t)(b * 8 + h) * 1024 + l) * 64 + d] = sv;
            else              vTb[((size_t)(b * 8 + h) * 64 + d) * 1024 + l] = sv;
        }
    }
}

// ---------- K2a: H = clip(qk/8) + e (fp32 out), sg = sigmoid(g) (bf16 scratch) ----------
// grid: 4096 = b(4) x ltile(64) x mtile(16); block 256 = 4 waves, each wave one m-16 subtile
__global__ void k_hsg(const float* __restrict__ edges, const short* __restrict__ qb,
                      const short* __restrict__ kb, const short* __restrict__ WcatT,
                      const float* __restrict__ bcat,
                      float* __restrict__ Hout, short* __restrict__ sgb){
    int bx = blockIdx.x;
    int mt = bx & 15;
    int lt = (bx >> 4) & 63;
    int b  = bx >> 10;
    int wave = threadIdx.x >> 6, lane = threadIdx.x & 63;
    int lr = lane & 15, lg = lane >> 4;
    int l0 = lt << 4;
    int m0 = mt * 64 + wave * 16;

    __shared__ short eg[4][16][16][24];   // [wave][l][m][ch(16)+pad] bf16

    bf16x8 wf = *(const bf16x8*)(WcatT + lr * 32 + lg * 8);   // A-frag: row=ch=lr, k=c
    f32x4 bc = *(const f32x4*)(bcat + lg * 4);

    // hoist q fragments: row=l=lr, k=d
    bf16x8 qf[8][2];
    #pragma unroll
    for (int h = 0; h < 8; ++h){
        #pragma unroll
        for (int half = 0; half < 2; ++half)
            qf[h][half] = *(const bf16x8*)(qb + ((size_t)(b * 8 + h) * 1024 + l0 + lr) * 64 + half * 32 + lg * 8);
    }

    // e,g: one MFMA per l: D[ch][m]
    f32x4 zero = {0.f, 0.f, 0.f, 0.f};
    #pragma unroll
    for (int l = 0; l < 16; ++l){
        const float* ep = edges + ((size_t)(b * 1024 + l0 + l) * 1024 + m0 + lr) * 32 + lg * 8;
        f32x4 e0 = *(const f32x4*)ep;
        f32x4 e1 = *(const f32x4*)(ep + 4);
        bf16x8 ef = pack8(e0, e1);        // B-frag: col=m=lr, k=c
        f32x4 d = MFMA16(wf, ef, zero);
        bf16x4 dv;
        #pragma unroll
        for (int r = 0; r < 4; ++r) dv[r] = f2bf(d[r] + bc[r]);
        *(bf16x4*)&eg[wave][l][lr][lg * 4] = dv;   // ch = 4*lg + r
    }

    // qk: S[h] D: col=m=lr, row=l=4*lg+r
    f32x4 S[8] = {};
    #pragma unroll
    for (int h = 0; h < 8; ++h){
        #pragma unroll
        for (int half = 0; half < 2; ++half){
            bf16x8 kf = *(const bf16x8*)(kb + ((size_t)(b * 8 + h) * 1024 + m0 + lr) * 64 + half * 32 + lg * 8);
            S[h] = MFMA16(qf[h][half], kf, S[h]);
        }
    }

    // epilogue: H fp32 out (coalesced, 8 heads packed), sg bf16
    #pragma unroll
    for (int r = 0; r < 4; ++r){
        int l = lg * 4 + r;
        bf16x8 e8 = *(const bf16x8*)&eg[wave][l][lr][0];
        bf16x8 g8 = *(const bf16x8*)&eg[wave][l][lr][8];
        float Hv[8]; bf16x8 sp;
        #pragma unroll
        for (int h = 0; h < 8; ++h){
            float s = S[h][r] * 0.125f;
            s = fminf(fmaxf(s, -5.f), 5.f);
            Hv[h] = s + bf2f(e8[h]);
            float g = bf2f(g8[h]);
            sp[h] = f2bf(1.f / (1.f + __expf(-g)));
        }
        size_t idx = ((size_t)(b * 1024 + l0 + l) * 1024 + m0 + lr) * 8;
        f32x4 h0 = {Hv[0], Hv[1], Hv[2], Hv[3]};
        f32x4 h1 = {Hv[4], Hv[5], Hv[6], Hv[7]};
        *(f32x4*)(Hout + idx)     = h0;
        *(f32x4*)(Hout + idx + 4) = h1;
        *(bf16x8*)(sgb + idx)     = sp;
    }
}

// ---------- K2b: online softmax + gated PV ----------
// grid: 256 = b(4) x ltile(64); block 512 = 8 waves, wave = one head, 16 l-rows
__global__ void k_pv(const float* __restrict__ Hout, const short* __restrict__ sgb,
                     const short* __restrict__ vTb, float* __restrict__ attn){
    int b  = blockIdx.x >> 6;
    int lt = blockIdx.x & 63;
    int h    = threadIdx.x >> 6;
    int lane = threadIdx.x & 63;
    int lr = lane & 15, lg = lane >> 4;
    int l0 = lt << 4;

    f32x4 O[4] = {};
    float mrun = -1e30f, lrun = 0.f;

    const float* Hrow  = Hout + ((size_t)(b * 1024 + l0 + lr) * 1024) * 8 + h;
    const short* Srow  = sgb  + ((size_t)(b * 1024 + l0 + lr) * 1024) * 8 + h;
    const short* vbase = vTb  + (size_t)(b * 8 + h) * 64 * 1024;

    for (int m0 = 0; m0 < 1024; m0 += 32){
        int mb = m0 + lg * 8;
        float Hv[8], sgv[8];
        #pragma unroll
        for (int j = 0; j < 8; ++j) Hv[j]  = Hrow[(size_t)(mb + j) * 8];
        #pragma unroll
        for (int j = 0; j < 8; ++j) sgv[j] = bf2f(Srow[(size_t)(mb + j) * 8]);

        // row max over this 32-m step (row = lr)
        float sm = Hv[0];
        #pragma unroll
        for (int j = 1; j < 8; ++j) sm = fmaxf(sm, Hv[j]);
        sm = fmaxf(sm, __shfl_xor(sm, 16));
        sm = fmaxf(sm, __shfl_xor(sm, 32));
        float mnew  = fmaxf(mrun, sm);
        float scale = __expf(mrun - mnew);

        float psum = 0.f, Pv[8];
        #pragma unroll
        for (int j = 0; j < 8; ++j){
            float ex = __expf(Hv[j] - mnew);   // UNGATED for denominator
            psum += ex;
            Pv[j] = ex * sgv[j];               // gated numerator
        }
        psum += __shfl_xor(psum, 16);
        psum += __shfl_xor(psum, 32);
        lrun = lrun * scale + psum;
        mrun = mnew;

        // rescale O (rows = 4*lg + r; scale lives in lane = row index)
        float f0 = __shfl(scale, lg * 4 + 0);
        float f1 = __shfl(scale, lg * 4 + 1);
        float f2 = __shfl(scale, lg * 4 + 2);
        float f3 = __shfl(scale, lg * 4 + 3);
        #pragma unroll
        for (int dt = 0; dt < 4; ++dt){
            O[dt][0] *= f0; O[dt][1] *= f1; O[dt][2] *= f2; O[dt][3] *= f3;
        }

        bf16x8 pf;   // A-frag: row=l=lr, k=m (already in-layout)
        #pragma unroll
        for (int j = 0; j < 8; ++j) pf[j] = f2bf(Pv[j]);
        #pragma unroll
        for (int dt = 0; dt < 4; ++dt){
            bf16x8 vf = *(const bf16x8*)(vbase + (size_t)(dt * 16 + lr) * 1024 + mb);
            O[dt] = MFMA16(pf, vf, O[dt]);
        }
    }

    float inv = 1.f / lrun;
    float g0 = __shfl(inv, lg * 4 + 0);
    float g1 = __shfl(inv, lg * 4 + 1);
    float g2 = __shfl(inv, lg * 4 + 2);
    float g3 = __shfl(inv, lg * 4 + 3);
    #pragma unroll
    for (int dt = 0; dt < 4; ++dt){
        int d = dt * 16 + lr;
        float vals[4] = {O[dt][0] * g0, O[dt][1] * g1, O[dt][2] * g2, O[dt][3] * g3};
        #pragma unroll
        for (int r = 0; r < 4; ++r)
            attn[(size_t)(b * 1024 + l0 + lg * 4 + r) * 512 + d * 8 + h] = vals[r];
    }
}

// ---------- workspace layout ----------
#define OFF_WT    ((size_t)0)                 // 3*512*512*2 = 1.5 MB
#define OFF_WCAT  ((size_t)0x200000)          // 1 KB
#define OFF_BCAT  ((size_t)0x200400)          // 64 B
#define OFF_Q     ((size_t)0x400000)          // 4 MB
#define OFF_K     ((size_t)0x800000)          // 4 MB
#define OFF_VT    ((size_t)0xC00000)          // 4 MB
#define OFF_SG    ((size_t)0x1000000)         // 67.1 MB -> total ~84 MB

extern "C" void kernel_launch(void* const* d_in, const int* in_sizes, int n_in,
                              void* d_out, int out_size, void* d_ws, size_t ws_size,
                              hipStream_t stream) {
    const float* nodes = (const float*)d_in[0];
    const float* edges = (const float*)d_in[1];
    const float* Wq = (const float*)d_in[2];
    const float* bq = (const float*)d_in[3];
    const float* Wk = (const float*)d_in[4];
    const float* bk = (const float*)d_in[5];
    const float* Wv = (const float*)d_in[6];
    const float* bv = (const float*)d_in[7];
    const float* Wg = (const float*)d_in[8];
    const float* bg = (const float*)d_in[9];
    const float* We = (const float*)d_in[10];
    const float* be = (const float*)d_in[11];

    float* out_attn = (float*)d_out;
    float* out_H    = out_attn + (size_t)4 * 1024 * 512;

    char* ws = (char*)d_ws;
    short* WT    = (short*)(ws + OFF_WT);
    short* WcatT = (short*)(ws + OFF_WCAT);
    float* bcat  = (float*)(ws + OFF_BCAT);
    short* qb    = (short*)(ws + OFF_Q);
    short* kb    = (short*)(ws + OFF_K);
    short* vTb   = (short*)(ws + OFF_VT);
    short* sgb   = (short*)(ws + OFF_SG);

    k_prep_wt  <<<192, 256, 0, stream>>>(Wq, Wk, Wv, WT);
    k_prep_wcat<<<1, 512, 0, stream>>>(We, Wg, be, bg, WcatT, bcat);
    k_qkv      <<<1536, 256, 0, stream>>>(nodes, WT, bq, bk, bv, qb, kb, vTb);
    k_hsg      <<<4096, 256, 0, stream>>>(edges, qb, kb, WcatT, bcat, out_H, sgb);
    k_pv       <<<256, 512, 0, stream>>>(out_H, sgb, vTb, out_attn);
}

// Round 2
// 336.410 us; speedup vs baseline: 1.2437x; 1.2437x over previous
//
#include <hip/hip_runtime.h>
#include <hip/hip_bf16.h>
#include <stdint.h>

// ---------- types / helpers ----------
typedef float  f32x4  __attribute__((ext_vector_type(4)));
typedef short  bf16x8 __attribute__((ext_vector_type(8)));
typedef short  bf16x4 __attribute__((ext_vector_type(4)));

#define MFMA16(A,B,C) __builtin_amdgcn_mfma_f32_16x16x32_bf16(A,B,C,0,0,0)

__device__ __forceinline__ short f2bf(float x){
    union { float f; uint32_t u; } v; v.f = x;
    uint32_t r = v.u + 0x7fffu + ((v.u >> 16) & 1u);   // RNE
    return (short)(r >> 16);
}
__device__ __forceinline__ float bf2f(short x){
    union { uint32_t u; float f; } v; v.u = ((uint32_t)(uint16_t)x) << 16;
    return v.f;
}
__device__ __forceinline__ bf16x8 pack8(f32x4 a, f32x4 b){
    bf16x8 r;
    r[0]=f2bf(a[0]); r[1]=f2bf(a[1]); r[2]=f2bf(a[2]); r[3]=f2bf(a[3]);
    r[4]=f2bf(b[0]); r[5]=f2bf(b[1]); r[6]=f2bf(b[2]); r[7]=f2bf(b[3]);
    return r;
}

// ---------- K0a: transpose Wq/Wk/Wv (fp32 [k][o]) -> WT bf16 [w][o][k] ----------
__global__ void k_prep_wt(const float* __restrict__ Wq, const float* __restrict__ Wk,
                          const float* __restrict__ Wv, short* __restrict__ WT){
    int blk = blockIdx.x;            // 192 = 3 * 64 tiles
    int w  = blk >> 6;
    int t  = blk & 63;
    int k0 = (t >> 3) << 6;
    int o0 = (t & 7) << 6;
    const float* W = (w == 0) ? Wq : ((w == 1) ? Wk : Wv);
    __shared__ float tile[64][65];
    int tx = threadIdx.x & 63, ty = threadIdx.x >> 6;    // ty 0..3
    #pragma unroll
    for (int i = 0; i < 64; i += 4)
        tile[ty + i][tx] = W[(size_t)(k0 + ty + i) * 512 + o0 + tx];
    __syncthreads();
    short* out = WT + (size_t)w * 512 * 512;
    #pragma unroll
    for (int i = 0; i < 64; i += 4)
        out[(size_t)(o0 + ty + i) * 512 + k0 + tx] = f2bf(tile[tx][ty + i]);
}

// ---------- K0b: WcatT bf16 [16ch][32c] (ch<8: We, ch>=8: Wg), bcat f32[16] ----------
__global__ void k_prep_wcat(const float* __restrict__ We, const float* __restrict__ Wg,
                            const float* __restrict__ be, const float* __restrict__ bg,
                            short* __restrict__ WcatT, float* __restrict__ bcat){
    int t = threadIdx.x;             // 512 threads
    int ch = t >> 5, c = t & 31;
    float v = (ch < 8) ? We[c * 8 + ch] : Wg[c * 8 + (ch - 8)];
    WcatT[ch * 32 + c] = f2bf(v);
    if (t < 16) bcat[t] = (t < 8) ? be[t] : bg[t - 8];
}

// ---------- K0c: nodes fp32 -> bf16 (once, instead of 6x inside k_qkv) ----------
__global__ void k_prep_nodes(const float* __restrict__ nodes, short* __restrict__ nb){
    size_t i = ((size_t)blockIdx.x * 256 + threadIdx.x) * 8;
    f32x4 a = *(const f32x4*)(nodes + i);
    f32x4 b = *(const f32x4*)(nodes + i + 4);
    *(bf16x8*)(nb + i) = pack8(a, b);
}

// ---------- K1: QKV projections ----------
// out = nodes @ W + b; q,k -> [b][h][l][64] bf16 ; v -> [b][h][64][l] bf16 (transposed)
__global__ void k_qkv(const short* __restrict__ nodesbf, const short* __restrict__ WT,
                      const float* __restrict__ bq, const float* __restrict__ bk,
                      const float* __restrict__ bv,
                      short* __restrict__ qb, short* __restrict__ kb, short* __restrict__ vTb){
    int bx = blockIdx.x;             // 1536
    int lt = bx & 255;
    int ob = bx >> 8;                // 0..5
    int wave = threadIdx.x >> 6, lane = threadIdx.x & 63;
    int lr = lane & 15, lg = lane >> 4;
    int row0 = lt << 4;              // global row (b*1024+l), tile of 16
    int og = ob * 256 + wave * 64;   // global col 0..1535
    int w  = og >> 9;                // 0=q,1=k,2=v
    int oo = og & 511;

    const short* Wp = WT + (size_t)w * 512 * 512;
    f32x4 acc[4] = {};
    const short* arow = nodesbf + (size_t)(row0 + lr) * 512 + lg * 8;
    #pragma unroll
    for (int kk = 0; kk < 16; ++kk){
        bf16x8 af = *(const bf16x8*)(arow + kk * 32);
        #pragma unroll
        for (int s = 0; s < 4; ++s){
            const short* bp = Wp + (size_t)(oo + s * 16 + lr) * 512 + kk * 32 + lg * 8;
            bf16x8 bfv = *(const bf16x8*)bp;
            acc[s] = MFMA16(af, bfv, acc[s]);
        }
    }
    const float* bias = (w == 0) ? bq : ((w == 1) ? bk : bv);
    int b  = row0 >> 10;
    int lb = (row0 & 1023) + lg * 4;
    #pragma unroll
    for (int s = 0; s < 4; ++s){
        int o = oo + s * 16 + lr;
        float bsv = bias[o];
        int h = o & 7, d = o >> 3;
        #pragma unroll
        for (int r = 0; r < 4; ++r){
            float v = acc[s][r] + bsv;
            short sv = f2bf(v);
            int l = lb + r;
            if (w == 0)       qb [((size_t)(b * 8 + h) * 1024 + l) * 64 + d] = sv;
            else if (w == 1)  kb [((size_t)(b * 8 + h) * 1024 + l) * 64 + d] = sv;
            else              vTb[((size_t)(b * 8 + h) * 64 + d) * 1024 + l] = sv;
        }
    }
}

// ---------- K2a: H = clip(qk/8)+e (fp32 out), P = sigmoid(g)*exp(H) (bf16, [b][h][l][m]),
//             psum = per-16m partial sums of ungated exp(H) (fp32, [b][h][l][64]) ----------
// grid: 4096 = b(4) x ltile(64) x mtile(16); block 256 = 4 waves, each wave one m-16 subtile
// No max-tracking needed: H = clip(qk,±5) + e, |e| <~ 0.7 -> exp(H) <= ~300, fp32-safe.
__global__ void k_hsg(const float* __restrict__ edges, const short* __restrict__ qb,
                      const short* __restrict__ kb, const short* __restrict__ WcatT,
                      const float* __restrict__ bcat,
                      float* __restrict__ Hout, short* __restrict__ Pb,
                      float* __restrict__ psum){
    int bx = blockIdx.x;
    int mt = bx & 15;
    int lt = (bx >> 4) & 63;
    int b  = bx >> 10;
    int wave = threadIdx.x >> 6, lane = threadIdx.x & 63;
    int lr = lane & 15, lg = lane >> 4;
    int l0 = lt << 4;
    int m0 = mt * 64 + wave * 16;

    __shared__ short eg[4][16][16][24];   // [wave][l][m][ch(16)+pad] bf16

    // ---- qk phase first: qf registers die before the edges loop ----
    f32x4 S[8] = {};
    #pragma unroll
    for (int h = 0; h < 8; ++h){
        #pragma unroll
        for (int half = 0; half < 2; ++half){
            bf16x8 qf = *(const bf16x8*)(qb + ((size_t)(b * 8 + h) * 1024 + l0 + lr) * 64 + half * 32 + lg * 8);
            bf16x8 kf = *(const bf16x8*)(kb + ((size_t)(b * 8 + h) * 1024 + m0 + lr) * 64 + half * 32 + lg * 8);
            S[h] = MFMA16(qf, kf, S[h]);
        }
    }

    // ---- e,g phase: one MFMA per l: D[ch][m] ----
    bf16x8 wf = *(const bf16x8*)(WcatT + lr * 32 + lg * 8);   // A-frag: row=ch=lr, k=c
    f32x4 bc = *(const f32x4*)(bcat + lg * 4);
    f32x4 zero = {0.f, 0.f, 0.f, 0.f};
    #pragma unroll
    for (int l = 0; l < 16; ++l){
        const float* ep = edges + ((size_t)(b * 1024 + l0 + l) * 1024 + m0 + lr) * 32 + lg * 8;
        f32x4 e0 = *(const f32x4*)ep;
        f32x4 e1 = *(const f32x4*)(ep + 4);
        bf16x8 ef = pack8(e0, e1);        // B-frag: col=m=lr, k=c
        f32x4 d = MFMA16(wf, ef, zero);
        bf16x4 dv;
        #pragma unroll
        for (int r = 0; r < 4; ++r) dv[r] = f2bf(d[r] + bc[r]);
        *(bf16x4*)&eg[wave][l][lr][lg * 4] = dv;   // ch = 4*lg + r
    }

    // ---- epilogue: per lane (l = 4*lg+r, m = lr), all 8 heads ----
    #pragma unroll
    for (int r = 0; r < 4; ++r){
        int l = lg * 4 + r;
        bf16x8 e8 = *(const bf16x8*)&eg[wave][l][lr][0];
        bf16x8 g8 = *(const bf16x8*)&eg[wave][l][lr][8];
        float Hv[8], ex[8], sg[8];
        #pragma unroll
        for (int h = 0; h < 8; ++h){
            float s = S[h][r] * 0.125f;
            s = fminf(fmaxf(s, -5.f), 5.f);
            Hv[h] = s + bf2f(e8[h]);
            ex[h] = __expf(Hv[h]);
            sg[h] = __builtin_amdgcn_rcpf(1.f + __expf(-bf2f(g8[h])));
        }
        // H output, packed by h (coalesced dwordx4)
        size_t idx = ((size_t)(b * 1024 + l0 + l) * 1024 + m0 + lr) * 8;
        f32x4 h0 = {Hv[0], Hv[1], Hv[2], Hv[3]};
        f32x4 h1 = {Hv[4], Hv[5], Hv[6], Hv[7]};
        *(f32x4*)(Hout + idx)     = h0;
        *(f32x4*)(Hout + idx + 4) = h1;
        // P store (head-major, = PV fragment layout) + ungated row-sum partials
        #pragma unroll
        for (int h = 0; h < 8; ++h){
            Pb[((size_t)(b * 8 + h) * 1024 + l0 + l) * 1024 + m0 + lr] = f2bf(ex[h] * sg[h]);
            float t = ex[h];
            t += __shfl_xor(t, 1);
            t += __shfl_xor(t, 2);
            t += __shfl_xor(t, 4);
            t += __shfl_xor(t, 8);
            if (lr == 0)
                psum[((size_t)(b * 8 + h) * 1024 + l0 + l) * 64 + mt * 4 + wave] = t;
        }
    }
}

// ---------- K2b: O = (P @ v) / rowsum — pure streaming MFMA ----------
// grid: 256 = b(4) x ltile(64); block 512 = 8 waves, wave = one head
// Orientation: A = vT (row=d, k=m), B = P (col=l, k=m) -> D[d][l]: col=l=lr (inv is lane-local)
__global__ void k_pv(const short* __restrict__ Pb, const float* __restrict__ psum,
                     const short* __restrict__ vTb, float* __restrict__ attn){
    int b  = blockIdx.x >> 6;
    int lt = blockIdx.x & 63;
    int h    = threadIdx.x >> 6;
    int lane = threadIdx.x & 63;
    int lr = lane & 15, lg = lane >> 4;
    int l0 = lt << 4;

    const short* Prow  = Pb  + ((size_t)(b * 8 + h) * 1024 + l0 + lr) * 1024 + lg * 8;
    const short* vbase = vTb + (size_t)(b * 8 + h) * 64 * 1024 + (size_t)lr * 1024 + lg * 8;

    f32x4 O[4] = {};
    for (int m0 = 0; m0 < 1024; m0 += 32){
        bf16x8 pf = *(const bf16x8*)(Prow + m0);       // B-frag: col=l=lr, k=m
        #pragma unroll
        for (int dt = 0; dt < 4; ++dt){
            bf16x8 vf = *(const bf16x8*)(vbase + (size_t)dt * 16 * 1024 + m0);  // A: row=d
            O[dt] = MFMA16(vf, pf, O[dt]);
        }
    }

    // denominator: reduce 64 partials per (l=lr, h)
    const float* pp = psum + ((size_t)(b * 8 + h) * 1024 + l0 + lr) * 64 + lg * 16;
    f32x4 s0 = *(const f32x4*)pp;
    f32x4 s1 = *(const f32x4*)(pp + 4);
    f32x4 s2 = *(const f32x4*)(pp + 8);
    f32x4 s3 = *(const f32x4*)(pp + 12);
    float ds = (s0[0]+s0[1]+s0[2]+s0[3]) + (s1[0]+s1[1]+s1[2]+s1[3])
             + (s2[0]+s2[1]+s2[2]+s2[3]) + (s3[0]+s3[1]+s3[2]+s3[3]);
    ds += __shfl_xor(ds, 16);
    ds += __shfl_xor(ds, 32);
    float inv = __builtin_amdgcn_rcpf(ds);

    // stage normalized O into LDS, then block-coalesced write
    __shared__ float Os[16][516];
    #pragma unroll
    for (int dt = 0; dt < 4; ++dt){
        #pragma unroll
        for (int r = 0; r < 4; ++r)
            Os[lr][(dt * 16 + lg * 4 + r) * 8 + h] = O[dt][r] * inv;   // d = dt*16+4lg+r, l = lr
    }
    __syncthreads();
    int row = threadIdx.x >> 5;          // 0..15
    int cb  = (threadIdx.x & 31) * 16;   // 0..496
    float* dst = attn + ((size_t)(b * 1024 + l0 + row)) * 512 + cb;
    #pragma unroll
    for (int j = 0; j < 16; j += 4)
        *(f32x4*)(dst + j) = *(const f32x4*)&Os[row][cb + j];
}

// ---------- workspace layout ----------
#define OFF_WT    ((size_t)0x0000000)   // 1.5 MB
#define OFF_WCAT  ((size_t)0x0180000)   // 1 KB
#define OFF_BCAT  ((size_t)0x0180400)   // 64 B
#define OFF_NB    ((size_t)0x0200000)   // 4 MB (nodes bf16)
#define OFF_Q     ((size_t)0x0600000)   // 4 MB
#define OFF_K     ((size_t)0x0A00000)   // 4 MB
#define OFF_VT    ((size_t)0x0E00000)   // 4 MB
#define OFF_P     ((size_t)0x1200000)   // 64 MB (P bf16 [b][h][l][m])
#define OFF_PS    ((size_t)0x5200000)   // 8 MB (psum fp32 [b][h][l][64]) -> total ~94.4 MB

extern "C" void kernel_launch(void* const* d_in, const int* in_sizes, int n_in,
                              void* d_out, int out_size, void* d_ws, size_t ws_size,
                              hipStream_t stream) {
    const float* nodes = (const float*)d_in[0];
    const float* edges = (const float*)d_in[1];
    const float* Wq = (const float*)d_in[2];
    const float* bq = (const float*)d_in[3];
    const float* Wk = (const float*)d_in[4];
    const float* bk = (const float*)d_in[5];
    const float* Wv = (const float*)d_in[6];
    const float* bv = (const float*)d_in[7];
    const float* Wg = (const float*)d_in[8];
    const float* bg = (const float*)d_in[9];
    const float* We = (const float*)d_in[10];
    const float* be = (const float*)d_in[11];

    float* out_attn = (float*)d_out;
    float* out_H    = out_attn + (size_t)4 * 1024 * 512;

    char* ws = (char*)d_ws;
    short* WT    = (short*)(ws + OFF_WT);
    short* WcatT = (short*)(ws + OFF_WCAT);
    float* bcat  = (float*)(ws + OFF_BCAT);
    short* nb    = (short*)(ws + OFF_NB);
    short* qb    = (short*)(ws + OFF_Q);
    short* kb    = (short*)(ws + OFF_K);
    short* vTb   = (short*)(ws + OFF_VT);
    short* Pb    = (short*)(ws + OFF_P);
    float* psum  = (float*)(ws + OFF_PS);

    k_prep_wt   <<<192, 256, 0, stream>>>(Wq, Wk, Wv, WT);
    k_prep_wcat <<<1, 512, 0, stream>>>(We, Wg, be, bg, WcatT, bcat);
    k_prep_nodes<<<1024, 256, 0, stream>>>(nodes, nb);
    k_qkv       <<<1536, 256, 0, stream>>>(nb, WT, bq, bk, bv, qb, kb, vTb);
    k_hsg       <<<4096, 256, 0, stream>>>(edges, qb, kb, WcatT, bcat, out_H, Pb, psum);
    k_pv        <<<256, 512, 0, stream>>>(Pb, psum, vTb, out_attn);
}